// Round 1
// baseline (745.922 us; speedup 1.0000x reference)
//
#include <hip/hip_runtime.h>

#define ROWN 70
#define NUMB 8192
#define RR   4900      // 70*70
#define SFS  104       // row stride (bf16 elems) for SF / T tiles (16B-aligned, bank-friendly)
#define HSTR 84        // row stride for H / theta tiles

typedef __attribute__((ext_vector_type(8))) short short8;
typedef __attribute__((ext_vector_type(4))) float f32x4;

__device__ __forceinline__ short f2bf(float f) {
    union { float f; unsigned u; } v; v.f = f;
    unsigned r = v.u + 0x7fffu + ((v.u >> 16) & 1u);   // RNE to bf16
    return (short)(r >> 16);
}

struct LdsT {
    float d[80];
    short sSF[80 * SFS];   // SF (matmul1 A) ; also reused pattern for T below
    short sB[96 * HSTR];   // H (matmul1 B), then theta1 (matmul2 B)
    short sT[80 * SFS];    // T = SF@H (matmul2 A)
};

__global__ __launch_bounds__(256)
void sfc_kernel(const float* __restrict__ S, const float* __restrict__ F,
                const float* __restrict__ H, const float* __restrict__ A,
                const float* __restrict__ Th, float* __restrict__ out)
{
    __shared__ LdsT L;
    const int n    = blockIdx.x;
    const int tid  = threadIdx.x;
    const int lane = tid & 63;
    const int w    = tid >> 6;
    const size_t base = (size_t)n * RR;

    // ---- phase 0: zero all LDS (pad regions must be 0 for MFMA K/M/N padding)
    {
        int* z = (int*)&L;
        const int nwords = (int)(sizeof(LdsT) / 4);
        for (int i = tid; i < nwords; i += 256) z[i] = 0;
    }
    __syncthreads();

    // ---- phase 1a: d[r] = rsqrt(rowsum(A[n,r,:])) ; one row per wave iteration
    for (int r = w; r < ROWN; r += 4) {
        const float* Ar = A + base + r * ROWN;
        float s = Ar[lane];
        if (lane < ROWN - 64) s += Ar[64 + lane];
        #pragma unroll
        for (int off = 32; off > 0; off >>= 1) s += __shfl_xor(s, off);
        if (lane == 0) L.d[r] = rsqrtf(s);
    }
    // ---- phase 1b: stage H -> bf16 LDS [96][84] (pad stays 0)
    for (int e4 = tid; e4 < RR / 4; e4 += 256) {
        float4 hv = ((const float4*)(H + base))[e4];
        const float* hp = (const float*)&hv;
        int e = e4 * 4;
        #pragma unroll
        for (int q = 0; q < 4; ++q) {
            int ee = e + q;
            int i = ee / ROWN, j = ee - i * ROWN;
            L.sB[i * HSTR + j] = f2bf(hp[q]);
        }
    }
    __syncthreads();

    // ---- phase 2: stage SF = d_i * d_j * S * F -> bf16 LDS [80][104]
    for (int e4 = tid; e4 < RR / 4; e4 += 256) {
        float4 sv = ((const float4*)(S + base))[e4];
        float4 fv = ((const float4*)(F + base))[e4];
        const float* sp = (const float*)&sv;
        const float* fp = (const float*)&fv;
        int e = e4 * 4;
        #pragma unroll
        for (int q = 0; q < 4; ++q) {
            int ee = e + q;
            int i = ee / ROWN, j = ee - i * ROWN;
            L.sSF[i * SFS + j] = f2bf(L.d[i] * L.d[j] * sp[q] * fp[q]);
        }
    }
    __syncthreads();

    const int lrow = lane & 15;          // M-row / N-col within 16x16 tile
    const int lk8  = (lane >> 4) * 8;    // K sub-block of 8

    // ---- phase 3: T = SF @ H   (25 tiles of 16x16, K = 3 chunks of 32)
    for (int t = w; t < 25; t += 4) {
        int tm = t / 5, tn = t % 5;
        f32x4 acc = {0.f, 0.f, 0.f, 0.f};
        #pragma unroll
        for (int kb = 0; kb < 3; ++kb) {
            short8 a = *(const short8*)&L.sSF[(tm * 16 + lrow) * SFS + kb * 32 + lk8];
            short8 b;
            int k0  = kb * 32 + lk8;
            int col = tn * 16 + lrow;
            #pragma unroll
            for (int j = 0; j < 8; ++j) b[j] = L.sB[(k0 + j) * HSTR + col];
            acc = __builtin_amdgcn_mfma_f32_16x16x32_bf16(a, b, acc, 0, 0, 0);
        }
        #pragma unroll
        for (int i = 0; i < 4; ++i) {
            int row = (lane >> 4) * 4 + i;             // C/D: col=lane&15, row=(lane>>4)*4+i
            L.sT[(tm * 16 + row) * SFS + tn * 16 + lrow] = f2bf(acc[i]);
        }
    }
    __syncthreads();

    // ---- phase 4: stage theta1 into sB (overwrites H; same 4900 cells, pad still 0)
    for (int e4 = tid; e4 < RR / 4; e4 += 256) {
        float4 tv = ((const float4*)Th)[e4];
        const float* tp = (const float*)&tv;
        int e = e4 * 4;
        #pragma unroll
        for (int q = 0; q < 4; ++q) {
            int ee = e + q;
            int i = ee / ROWN, j = ee - i * ROWN;
            L.sB[i * HSTR + j] = f2bf(tp[q]);
        }
    }
    __syncthreads();

    // ---- phase 5: out = relu(T @ theta1), fp32 store
    for (int t = w; t < 25; t += 4) {
        int tm = t / 5, tn = t % 5;
        f32x4 acc = {0.f, 0.f, 0.f, 0.f};
        #pragma unroll
        for (int kb = 0; kb < 3; ++kb) {
            short8 a = *(const short8*)&L.sT[(tm * 16 + lrow) * SFS + kb * 32 + lk8];
            short8 b;
            int k0  = kb * 32 + lk8;
            int col = tn * 16 + lrow;
            #pragma unroll
            for (int j = 0; j < 8; ++j) b[j] = L.sB[(k0 + j) * HSTR + col];
            acc = __builtin_amdgcn_mfma_f32_16x16x32_bf16(a, b, acc, 0, 0, 0);
        }
        #pragma unroll
        for (int i = 0; i < 4; ++i) {
            int row = tm * 16 + (lane >> 4) * 4 + i;
            int cn  = tn * 16 + lrow;
            if (row < ROWN && cn < ROWN) {
                float v = acc[i];
                out[base + row * ROWN + cn] = v > 0.f ? v : 0.f;
            }
        }
    }
}

extern "C" void kernel_launch(void* const* d_in, const int* in_sizes, int n_in,
                              void* d_out, int out_size, void* d_ws, size_t ws_size,
                              hipStream_t stream) {
    const float* S  = (const float*)d_in[0];
    const float* F  = (const float*)d_in[1];
    const float* H  = (const float*)d_in[2];
    const float* A  = (const float*)d_in[3];
    const float* Th = (const float*)d_in[4];
    float* out = (float*)d_out;
    sfc_kernel<<<NUMB, 256, 0, stream>>>(S, F, H, A, Th, out);
}